// Round 16
// baseline (126.308 us; speedup 1.0000x reference)
//
#include <hip/hip_runtime.h>
#include <hip/hip_bf16.h>

// Problem constants
#define D_MODEL 768
#define NH 12
#define HD 64
#define BATCH 4
#define SEQ 2048
#define BHN (BATCH*NH)        // 48
#define MROWS (BATCH*SEQ)     // 8192

typedef unsigned short u16;
typedef unsigned int u32;
typedef __attribute__((ext_vector_type(8))) short short8;
typedef __attribute__((ext_vector_type(4))) float f32x4;

__device__ inline u16 f2bf(float f){
  union { __hip_bfloat16 h; u16 u; } cv; cv.h = __float2bfloat16(f); return cv.u;
}
__device__ inline u32 pack_bf2(float a, float b){
  return (u32)f2bf(a) | ((u32)f2bf(b) << 16);
}
// Fast packed f32->bf16 via v_perm_b32 builtin (no inline asm): round-half-up
// (adds 0x8000 then truncates). Valid ONLY for finite non-NaN inputs -- used
// for P = exp2(...) in (0, 256], never NaN/Inf. 3 VALU inst vs ~11 for 2x RNE.
// low16 = bf16(a), high16 = bf16(b)  (same layout as pack_bf2).
__device__ inline u32 pack_bf2_rn(float a, float b){
  union { float f; u32 u; } ua, ub;
  ua.f = a; ub.f = b;
  u32 ra = ua.u + 0x8000u;
  u32 rb = ub.u + 0x8000u;
  // combined {rb:ra} bytes: ra=0..3, rb=4..7; pick {rb3,rb2,ra3,ra2}
  return __builtin_amdgcn_perm(rb, ra, 0x07060302);
}

// async global->LDS, 16B per lane. LDS dest = wave-uniform base + lane*16.
__device__ inline void async_copy16(const void* g, void* l){
  __builtin_amdgcn_global_load_lds(
      (const __attribute__((address_space(1))) void*)g,
      (__attribute__((address_space(3))) void*)l, 16, 0, 0);
}

// ---------------- fused prep: cast x (blocks 0..6143), transpose Wqkv
// (6144..6575), transpose Wout (6576..6719) ----------------
__global__ void prep_kernel(const float* __restrict__ x, u16* __restrict__ x_bf,
                            const float* __restrict__ wqkv, u16* __restrict__ wqkv_t,
                            const float* __restrict__ wout, u16* __restrict__ wout_t)
{
  __shared__ u16 tile[64][65];
  const int bid = blockIdx.x, tid = threadIdx.x;
  if (bid < 6144){
    int i = bid*256 + tid;
    const float4 v = ((const float4*)x)[i];
    ushort4 o;
    o.x = f2bf(v.x); o.y = f2bf(v.y); o.z = f2bf(v.z); o.w = f2bf(v.w);
    ((ushort4*)x_bf)[i] = o;
    return;
  }
  const float* w; u16* wt; int K, N, t;
  if (bid < 6576){ w = wqkv; wt = wqkv_t; K = 768; N = 2304; t = bid - 6144; }
  else           { w = wout; wt = wout_t; K = 768; N = 768;  t = bid - 6576; }
  int k0 = (t % 12)*64, n0 = (t / 12)*64;
  int c = tid & 63, r0 = tid >> 6;
  #pragma unroll
  for (int r = r0; r < 64; r += 4)
    tile[c][r] = f2bf(w[(size_t)(k0+r)*N + n0 + c]);
  __syncthreads();
  #pragma unroll
  for (int r = r0; r < 64; r += 4)
    wt[(size_t)(n0+r)*K + k0 + c] = tile[r][c];
}

// ---------------- bf16 GEMM (QKV): 128x192 tile, BK=32 (frozen, R13) ----------------
__launch_bounds__(256, 3)
__global__ void gemm_qkv(const u16* __restrict__ A, const u16* __restrict__ Bt,
                         const float* __restrict__ bias,
                         u16* __restrict__ oq, u16* __restrict__ ok, u16* __restrict__ ovt,
                         int M, int N, int K)
{
  __shared__ alignas(16) char smem[40960];   // 2 bufs x (A 8KB + B 12KB)
  const int tid = threadIdx.x, wave = tid>>6, lane = tid&63;
  const int lr = lane&15, lg = lane>>4;
  const int m0 = blockIdx.x*128, n0 = blockIdx.y*192;
  const int wr = (wave>>1)*64, wc = (wave&1)*96;
  f32x4 acc[4][6] = {};
  const int srowA = wave*32 + (lane>>2);             // A staging row (+i*16)
  const int srowB = wave*16 + (lane>>2);             // B staging row (+i*64)
  const int schk = (lane&3) ^ ((lane>>3)&3);         // swizzled source granule
  const int fo   = ((lg ^ ((lr>>1)&3)) << 4);        // swizzled frag byte offset

  auto stage = [&](int kt, int buf){
    char* Ab = smem + buf*20480;
    char* Bb = Ab + 8192;
    #pragma unroll
    for (int i = 0; i < 2; i++){
      int r = srowA + i*16;
      async_copy16(A + (size_t)(m0 + r)*K + kt + schk*8, Ab + (wave*32 + i*16)*64);
    }
    #pragma unroll
    for (int i = 0; i < 3; i++){
      int r = srowB + i*64;
      async_copy16(Bt + (size_t)(n0 + r)*K + kt + schk*8, Bb + i*4096 + wave*1024);
    }
  };

  const int NT = K >> 5;
  stage(0, 0);
  for (int t = 0; t < NT; t++){
    const int c = t & 1;
    asm volatile("s_waitcnt vmcnt(0)" ::: "memory");
    __builtin_amdgcn_s_barrier();
    if (t+1 < NT) stage((t+1)<<5, c^1);

    const char* Ac = smem + c*20480;
    const char* Bc = Ac + 8192;
    short8 a[4], b[6];
    #pragma unroll
    for (int mi = 0; mi < 4; mi++)
      a[mi] = *(const short8*)(Ac + (wr + mi*16 + lr)*64 + fo);
    #pragma unroll
    for (int ni = 0; ni < 6; ni++)
      b[ni] = *(const short8*)(Bc + (wc + ni*16 + lr)*64 + fo);
    #pragma unroll
    for (int mi = 0; mi < 4; mi++)
      #pragma unroll
      for (int ni = 0; ni < 6; ni++)
        acc[mi][ni] = __builtin_amdgcn_mfma_f32_16x16x32_bf16(a[mi], b[ni], acc[mi][ni], 0, 0, 0);
  }

  // epilogue: C row = (lane>>4)*4 + j, col = lane&15  [verified C/D layout]
  #pragma unroll
  for (int mi = 0; mi < 4; mi++)
  #pragma unroll
  for (int ni = 0; ni < 6; ni++)
  #pragma unroll
  for (int j = 0; j < 4; j++){
    int m = m0 + wr + mi*16 + lg*4 + j;
    int n = n0 + wc + ni*16 + lr;
    float v = acc[mi][ni][j] + bias[n];
    int b_ = m >> 11, s = m & 2047;
    int ty = (n >= 1536) ? 2 : (n >= 768 ? 1 : 0);
    int hn = n - ty*768;
    int h = hn >> 6, d = hn & 63;
    size_t base = (size_t)(b_*NH + h);
    if (ty == 0)      oq [(base*SEQ + s)*HD + d] = f2bf(v * 0.1803368801f); // fold 0.125*log2e into Q
    else if (ty == 1) ok [(base*SEQ + s)*HD + d] = f2bf(v);
    else              ovt[(base*HD + d)*SEQ + s] = f2bf(v);   // V stored transposed
  }
}

// ---------------- bf16 GEMM (out-proj): 64x128 tile, uniform 3 blocks/CU ----
__launch_bounds__(256)
__global__ void gemm_out64(const u16* __restrict__ A, const u16* __restrict__ Bt,
                           const float* __restrict__ bias, float* __restrict__ outf,
                           int M, int N, int K)
{
  __shared__ alignas(16) char smem[24576];   // 2 bufs x (A 4KB + B 8KB)
  const int tid = threadIdx.x, wave = tid>>6, lane = tid&63;
  const int lr = lane&15, lg = lane>>4;
  const int m0 = blockIdx.x*64, n0 = blockIdx.y*128;
  const int wr = (wave>>1)*32, wc = (wave&1)*64;
  f32x4 acc[2][4] = {};
  const int srowB = wave*32 + (lane>>2);             // B staging row (+i*16)
  const int schk  = (lane&3) ^ ((lane>>3)&3);        // swizzled source granule (B)
  const int rowA  = tid >> 2;                        // A staging row (1 chunk/thread)
  const int schkA = (tid&3) ^ ((tid>>3)&3);          // swizzled source granule (A)
  const int fo    = ((lg ^ ((lr>>1)&3)) << 4);       // swizzled frag byte offset

  auto stage = [&](int kt, int buf){
    char* Ab = smem + buf*12288;
    char* Bb = Ab + 4096;
    async_copy16(A + (size_t)(m0 + rowA)*K + kt + schkA*8, Ab + (wave*16)*64);
    #pragma unroll
    for (int i = 0; i < 2; i++){
      int r = srowB + i*16;
      async_copy16(Bt + (size_t)(n0 + r)*K + kt + schk*8, Bb + (wave*32 + i*16)*64);
    }
  };

  const int NT = K >> 5;
  stage(0, 0);
  for (int t = 0; t < NT; t++){
    const int c = t & 1;
    asm volatile("s_waitcnt vmcnt(0)" ::: "memory");
    __builtin_amdgcn_s_barrier();
    if (t+1 < NT) stage((t+1)<<5, c^1);

    const char* Ac = smem + c*12288;
    const char* Bc = Ac + 4096;
    short8 a[2], b[4];
    #pragma unroll
    for (int mi = 0; mi < 2; mi++)
      a[mi] = *(const short8*)(Ac + (wr + mi*16 + lr)*64 + fo);
    #pragma unroll
    for (int ni = 0; ni < 4; ni++)
      b[ni] = *(const short8*)(Bc + (wc + ni*16 + lr)*64 + fo);
    #pragma unroll
    for (int mi = 0; mi < 2; mi++)
      #pragma unroll
      for (int ni = 0; ni < 4; ni++)
        acc[mi][ni] = __builtin_amdgcn_mfma_f32_16x16x32_bf16(a[mi], b[ni], acc[mi][ni], 0, 0, 0);
  }

  #pragma unroll
  for (int mi = 0; mi < 2; mi++)
  #pragma unroll
  for (int ni = 0; ni < 4; ni++)
  #pragma unroll
  for (int j = 0; j < 4; j++){
    int m = m0 + wr + mi*16 + lg*4 + j;
    int n = n0 + wc + ni*16 + lr;
    outf[(size_t)m*N + n] = acc[mi][ni][j] + bias[n];
  }
}

// ---------------- flash attention: merged causal pair-sweep ----------------
// R16: P-pack via v_perm_b32 BUILTIN (pack_bf2_rn: +0x8000 round-half-up,
// 3 inst/pair vs ~11) -- safe for P in (0,256], no NaN/Inf path. Final output
// epilogue keeps exact RNE f2bf. Rest identical to R15.
__launch_bounds__(256, 3)
__global__ void attn_kernel(const u16* __restrict__ q, const u16* __restrict__ k,
                            const u16* __restrict__ vt, u16* __restrict__ aout)
{
  __shared__ alignas(16) char smem[53248];
  const int b1 = blockIdx.x;                 // 0..767
  const int xcd = b1 & 7, grp = b1 >> 3;     // grp 0..95
  const int bh = xcd*6 + (grp >> 4);         // 6 heads per XCD (L2 locality)
  const int p  = grp & 15;                   // lo tile index 0..15
  const int hi = 31 - p;                     // hi tile index 16..31
  const int tid = threadIdx.x, wave = tid>>6, lane = tid&63;
  const int lr = lane&15, lg = lane>>4;
  const int b_ = bh / NH, h_ = bh % NH;
  const u16* qp = q  + (size_t)bh*SEQ*HD;
  const u16* kp = k  + (size_t)bh*SEQ*HD;
  const u16* vp = vt + (size_t)bh*HD*SEQ;
  char* Pw = smem + 32768 + wave*5120;
  const int fswz = (lr&7)<<4;
  const int c8s = (lane&7) ^ (lane>>3);
  const int nkv = hi + 1;

  // hoisted P-LDS write offsets (loop-invariant per ni)
  int po[4];
  #pragma unroll
  for (int ni = 0; ni < 4; ni++){
    int tl = lr + 16*(((ni&1)<<1) | (lg>>1));
    int wb = ((ni>>1)<<2) | ((lg&1)<<1);
    po[ni] = tl*40 + wb*4;
  }

  auto stageKV = [&](int kv0, int buf){
    char* Kb = smem + buf*16384;
    char* Vb = Kb + 8192;
    #pragma unroll
    for (int r = 0; r < 2; r++){
      int row = wave*16 + r*8 + (lane>>3);
      async_copy16(kp + (size_t)(kv0 + row)*HD + c8s*8, Kb + (wave*16 + r*8)*128);
      async_copy16(vp + (size_t)row*SEQ + kv0 + c8s*8,  Vb + (wave*16 + r*8)*128);
    }
  };

  const int qrow[2] = { hi*64 + wave*16 + lr, p*64 + wave*16 + lr };

  short8 bq[2][2];
  #pragma unroll
  for (int h = 0; h < 2; h++)
    #pragma unroll
    for (int ks = 0; ks < 2; ks++)
      bq[h][ks] = *(const short8*)(qp + (size_t)qrow[h]*HD + ks*32 + lg*8);

  float mrow[2] = {-INFINITY, -INFINITY};
  float lsum[2] = {0.f, 0.f};
  f32x4 o[4][2] = {};

  stageKV(0, 0);

  auto softmax_pack = [&](f32x4 (&s)[4][2], int h, bool domask, int kv0, int qr){
    if (domask){
      #pragma unroll
      for (int ni = 0; ni < 4; ni++)
        #pragma unroll
        for (int jj = 0; jj < 4; jj++){
          int col = kv0 + ni*16 + lg*4 + jj;
          if (col > qr) s[ni][h][jj] = -1e30f;
        }
    }
    // max3-shaped 16-value reduce (clang fuses fmaxf(fmaxf(a,b),c) -> v_max3)
    float v0 = fmaxf(fmaxf(s[0][h][0], s[0][h][1]), s[0][h][2]);
    float v1 = fmaxf(fmaxf(s[0][h][3], s[1][h][0]), s[1][h][1]);
    float v2 = fmaxf(fmaxf(s[1][h][2], s[1][h][3]), s[2][h][0]);
    float v3 = fmaxf(fmaxf(s[2][h][1], s[2][h][2]), s[2][h][3]);
    float v4 = fmaxf(fmaxf(s[3][h][0], s[3][h][1]), s[3][h][2]);
    float vloc = fmaxf(fmaxf(fmaxf(v0, v1), fmaxf(v2, v3)), fmaxf(v4, s[3][h][3]));
    if (!__all(vloc - mrow[h] <= 8.0f)){
      float v = fmaxf(vloc, __shfl_xor(vloc, 16));
      v = fmaxf(v, __shfl_xor(v, 32));
      float mn = fmaxf(mrow[h], v);
      float alpha = __builtin_amdgcn_exp2f(mrow[h] - mn);
      mrow[h] = mn;
      lsum[h] *= alpha;
      #pragma unroll
      for (int ni = 0; ni < 4; ni++)
        #pragma unroll
        for (int jj = 0; jj < 4; jj++)
          o[ni][h][jj] *= alpha;
    }
    const float mn = mrow[h];
    char* hb = Pw + h*2560;
    float psum = 0.f;
    #pragma unroll
    for (int ni = 0; ni < 4; ni++){
      float p0 = __builtin_amdgcn_exp2f(s[ni][h][0] - mn);
      float p1 = __builtin_amdgcn_exp2f(s[ni][h][1] - mn);
      float p2 = __builtin_amdgcn_exp2f(s[ni][h][2] - mn);
      float p3 = __builtin_amdgcn_exp2f(s[ni][h][3] - mn);
      psum += (p0+p1) + (p2+p3);
      *(u32*)(hb + po[ni])     = pack_bf2_rn(p0, p1);
      *(u32*)(hb + po[ni] + 4) = pack_bf2_rn(p2, p3);
    }
    lsum[h] += psum;
  };

  auto read_pb = [&](int h, short8& r0, short8& r1){
    const char* hb = Pw + h*2560 + (size_t)lane*40;
    union { u32 w[4]; short8 v; } a, b;
    a.w[0] = *(const u32*)(hb);      a.w[1] = *(const u32*)(hb + 4);
    a.w[2] = *(const u32*)(hb + 8);  a.w[3] = *(const u32*)(hb + 12);
    b.w[0] = *(const u32*)(hb + 16); b.w[1] = *(const u32*)(hb + 20);
    b.w[2] = *(const u32*)(hb + 24); b.w[3] = *(const u32*)(hb + 28);
    r0 = a.v; r1 = b.v;
  };

  int kvb = 0;

  #pragma unroll 1
  for (; kvb <= p; kvb++){
    const int c = kvb & 1;
    const int kv0 = kvb*64;
    asm volatile("s_waitcnt vmcnt(0)" ::: "memory");
    __builtin_amdgcn_s_barrier();
    if (kvb+1 < nkv) stageKV(kv0 + 64, c^1);

    const char* Kb = smem + c*16384;
    const char* Vb = Kb + 8192;

    f32x4 s[4][2] = {};
    __builtin_amdgcn_s_setprio(1);
    #pragma unroll
    for (int ni = 0; ni < 4; ni++){
      short8 k0 = *(const short8*)(Kb + (ni*16+lr)*128 + ((lg*16) ^ fswz));
      short8 k1 = *(const short8*)(Kb + (ni*16+lr)*128 + ((64 + lg*16) ^ fswz));
      #pragma unroll
      for (int h = 0; h < 2; h++){
        s[ni][h] = __builtin_amdgcn_mfma_f32_16x16x32_bf16(k0, bq[h][0], s[ni][h], 0,0,0);
        s[ni][h] = __builtin_amdgcn_mfma_f32_16x16x32_bf16(k1, bq[h][1], s[ni][h], 0,0,0);
      }
    }
    __builtin_amdgcn_s_setprio(0);

    softmax_pack(s, 0, false, kv0, qrow[0]);
    softmax_pack(s, 1, kvb == p, kv0, qrow[1]);

    short8 pb[2][2];
    read_pb(0, pb[0][0], pb[0][1]);
    read_pb(1, pb[1][0], pb[1][1]);

    __builtin_amdgcn_s_setprio(1);
    #pragma unroll
    for (int ni = 0; ni < 4; ni++){
      short8 v0 = *(const short8*)(Vb + (ni*16+lr)*128 + ((lg*16) ^ fswz));
      short8 v1 = *(const short8*)(Vb + (ni*16+lr)*128 + ((64 + lg*16) ^ fswz));
      #pragma unroll
      for (int h = 0; h < 2; h++){
        o[ni][h] = __builtin_amdgcn_mfma_f32_16x16x32_bf16(v0, pb[h][0], o[ni][h], 0,0,0);
        o[ni][h] = __builtin_amdgcn_mfma_f32_16x16x32_bf16(v1, pb[h][1], o[ni][h], 0,0,0);
      }
    }
    __builtin_amdgcn_s_setprio(0);
  }

  #pragma unroll 1
  for (; kvb < nkv; kvb++){
    const int c = kvb & 1;
    const int kv0 = kvb*64;
    asm volatile("s_waitcnt vmcnt(0)" ::: "memory");
    __builtin_amdgcn_s_barrier();
    if (kvb+1 < nkv) stageKV(kv0 + 64, c^1);

    const char* Kb = smem + c*16384;
    const char* Vb = Kb + 8192;

    f32x4 s[4][2];
    #pragma unroll
    for (int ni = 0; ni < 4; ni++) s[ni][0] = (f32x4){0.f,0.f,0.f,0.f};
    __builtin_amdgcn_s_setprio(1);
    #pragma unroll
    for (int ni = 0; ni < 4; ni++){
      short8 k0 = *(const short8*)(Kb + (ni*16+lr)*128 + ((lg*16) ^ fswz));
      short8 k1 = *(const short8*)(Kb + (ni*16+lr)*128 + ((64 + lg*16) ^ fswz));
      s[ni][0] = __builtin_amdgcn_mfma_f32_16x16x32_bf16(k0, bq[0][0], s[ni][0], 0,0,0);
      s[ni][0] = __builtin_amdgcn_mfma_f32_16x16x32_bf16(k1, bq[0][1], s[ni][0], 0,0,0);
    }
    __builtin_amdgcn_s_setprio(0);

    softmax_pack(s, 0, kvb == hi, kv0, qrow[0]);

    short8 pb0, pb1;
    read_pb(0, pb0, pb1);

    __builtin_amdgcn_s_setprio(1);
    #pragma unroll
    for (int ni = 0; ni < 4; ni++){
      short8 v0 = *(const short8*)(Vb + (ni*16+lr)*128 + ((lg*16) ^ fswz));
      short8 v1 = *(const short8*)(Vb + (ni*16+lr)*128 + ((64 + lg*16) ^ fswz));
      o[ni][0] = __builtin_amdgcn_mfma_f32_16x16x32_bf16(v0, pb0, o[ni][0], 0,0,0);
      o[ni][0] = __builtin_amdgcn_mfma_f32_16x16x32_bf16(v1, pb1, o[ni][0], 0,0,0);
    }
    __builtin_amdgcn_s_setprio(0);
  }

  #pragma unroll
  for (int h = 0; h < 2; h++){
    float ls = lsum[h];
    ls += __shfl_xor(ls, 16);
    ls += __shfl_xor(ls, 32);
    float inv = 1.0f / ls;
    u16* orow = aout + ((size_t)b_*SEQ + qrow[h])*D_MODEL + h_*HD;
    #pragma unroll
    for (int ni = 0; ni < 4; ni++){
      ushort4 w;
      w.x = f2bf(o[ni][h][0]*inv);
      w.y = f2bf(o[ni][h][1]*inv);
      w.z = f2bf(o[ni][h][2]*inv);
      w.w = f2bf(o[ni][h][3]*inv);
      *(ushort4*)(orow + ni*16 + lg*4) = w;
    }
  }
}

extern "C" void kernel_launch(void* const* d_in, const int* in_sizes, int n_in,
                              void* d_out, int out_size, void* d_ws, size_t ws_size,
                              hipStream_t stream)
{
  const float* x    = (const float*)d_in[0];
  const float* Wqkv = (const float*)d_in[1];
  const float* bqkv = (const float*)d_in[2];
  const float* Wout = (const float*)d_in[3];
  const float* bout = (const float*)d_in[4];
  float* out = (float*)d_out;
  char* ws = (char*)d_ws;

  // workspace layout (bytes)
  u16* x_bf   = (u16*)(ws + 0);          // 8192x768   bf16 = 12,582,912
  u16* wqkv_t = (u16*)(ws + 12582912);   // 2304x768   bf16 =  3,538,944
  u16* wout_t = (u16*)(ws + 16121856);   //  768x768   bf16 =  1,179,648
  u16* qb     = (u16*)(ws + 17301504);   // [48][2048][64]  = 12,582,912
  u16* kb     = (u16*)(ws + 29884416);   // [48][2048][64]  = 12,582,912
  u16* vtb    = (u16*)(ws + 42467328);   // [48][64][2048]  = 12,582,912
  u16* attnb  = (u16*)(ws + 55050240);   // 8192x768   bf16 = 12,582,912

  prep_kernel<<<6720, 256, 0, stream>>>(x, x_bf, Wqkv, wqkv_t, Wout, wout_t);

  gemm_qkv<<<dim3(64, 12), 256, 0, stream>>>(x_bf, wqkv_t, bqkv,
                                             qb, kb, vtb, MROWS, 3*D_MODEL, D_MODEL);

  attn_kernel<<<768, 256, 0, stream>>>(qb, kb, vtb, attnb);

  gemm_out64<<<dim3(128, 6), 256, 0, stream>>>(attnb, wout_t, bout, out,
                                               MROWS, D_MODEL, D_MODEL);
}